// Round 6
// baseline (764.536 us; speedup 1.0000x reference)
//
#include <hip/hip_runtime.h>
#include <math.h>

// L2ClusterCentroid: N=1e6 rows, D=128, C=100.
// assign = argmax(logits, -1); centroids = segment_mean(embedding, assign);
// out[c] = counts[c]>0 ? ||centers[c] - centroids[c]||_2 : 0
//
// Round-5 (resubmit; prior attempt hit container failure before running):
// rounds 2-4 were latency-bound (~1 outstanding load/CU) because the
// wave-cooperative argmax put full-wave ds_bpermute shuffles + lgkmcnt drains
// on every row's critical path. New structure removes wave-wide shuffles:
//  K1 argmax:     4 lanes/row, per-lane serial float4 scan (64x MLP),
//                 quad-only shfl_xor(1,2) merge -> DPP, VALU-speed.
//  K2 accumulate: 1 coalesced assign load / 64 rows, v_readlane broadcast,
//                 uniform-base LDS atomics (2-way bank alias = free).
//  K3 final:      fixed-order partial reduction + distance epilogue.

#define NROWS 1000000
#define DIM   128
#define NCLS  100
#define SLICE (NCLS * DIM + NCLS)   // 12900 floats per block partial
#define P2_THREADS 512

// ---------------- K1: argmax over logits rows ----------------
__global__ __launch_bounds__(256)
void l2cc_argmax(const float* __restrict__ logits, int* __restrict__ assign)
{
    const int tid = threadIdx.x;
    const int row = blockIdx.x * 64 + (tid >> 2);
    const int p   = tid & 3;
    if (row >= NROWS) return;

    const float4* lrow = reinterpret_cast<const float4*>(logits + (size_t)row * NCLS);
    float best = -INFINITY;
    int   bi   = 0x7fffffff;
    #pragma unroll
    for (int i = 0; i < 6; ++i) {
        const float4 v = lrow[i * 4 + p];       // cols 16i+4p .. +3
        const int c0 = i * 16 + p * 4;
        if (v.x > best) { best = v.x; bi = c0;     }
        if (v.y > best) { best = v.y; bi = c0 + 1; }
        if (v.z > best) { best = v.z; bi = c0 + 2; }
        if (v.w > best) { best = v.w; bi = c0 + 3; }
    }
    {   // tail cols 96..99
        const float t = logits[(size_t)row * NCLS + 96 + p];
        if (t > best) { best = t; bi = 96 + p; }
    }
    // merge across the 4 lanes of this row: quad_perm DPP, no LDS pipe
    #pragma unroll
    for (int off = 1; off <= 2; off <<= 1) {
        const float ov = __shfl_xor(best, off, 64);
        const int   oi = __shfl_xor(bi,   off, 64);
        if (ov > best || (ov == best && oi < bi)) { best = ov; bi = oi; }
    }
    if (p == 0) assign[row] = bi;
}

// ---------------- K2: segment-sum embedding into per-block partials ----------------
__global__ __launch_bounds__(P2_THREADS, 4)
void l2cc_accum(const float* __restrict__ emb,
                const int* __restrict__ assign,
                float* __restrict__ partial,
                int rows_per_block)
{
    __shared__ float s_acc[SLICE];  // sums permuted: e.x->slot lane, e.y->slot 64+lane
    const int tid = threadIdx.x;
    for (int i = tid; i < SLICE; i += P2_THREADS) s_acc[i] = 0.0f;
    __syncthreads();

    const int wave = tid >> 6;
    const int lane = tid & 63;
    const int start = blockIdx.x * rows_per_block;
    const int end   = min(start + rows_per_block, NROWS);

    for (int r0 = start + wave * 64; r0 < end; r0 += (P2_THREADS / 64) * 64) {
        const int n = min(64, end - r0);
        const int a = (lane < n) ? assign[r0 + lane] : 0;   // 1 coalesced load / 64 rows
        if (lane < n) atomicAdd(s_acc + NCLS * DIM + a, 1.0f);

        if (n == 64) {
            #pragma unroll
            for (int jc = 0; jc < 64; jc += 8) {
                float2 e[8];
                #pragma unroll
                for (int j = 0; j < 8; ++j)
                    e[j] = *reinterpret_cast<const float2*>(
                        emb + (size_t)(r0 + jc + j) * DIM + lane * 2);
                #pragma unroll
                for (int j = 0; j < 8; ++j) {
                    const int k = __shfl(a, jc + j, 64);   // compile-time lane -> v_readlane
                    float* base = s_acc + k * DIM;
                    atomicAdd(base + lane,      e[j].x);   // dim 2*lane
                    atomicAdd(base + 64 + lane, e[j].y);   // dim 2*lane+1
                }
            }
        } else {
            for (int j = 0; j < n; ++j) {
                const float2 e = *reinterpret_cast<const float2*>(
                    emb + (size_t)(r0 + j) * DIM + lane * 2);
                const int k = __shfl(a, j, 64);
                float* base = s_acc + k * DIM;
                atomicAdd(base + lane,      e.x);
                atomicAdd(base + 64 + lane, e.y);
            }
        }
    }
    __syncthreads();

    float* p = partial + (size_t)blockIdx.x * SLICE;
    for (int i = tid; i < SLICE; i += P2_THREADS) p[i] = s_acc[i];
}

// ---------------- K3: fixed-order reduction + distance epilogue ----------------
__global__ __launch_bounds__(512)
void l2cc_final(const float* __restrict__ partial,
                const float* __restrict__ centers,
                float* __restrict__ out,
                int nblocks)
{
    const int c = blockIdx.x;          // 0..99
    const int t = threadIdx.x & 127;   // permuted slot
    const int g = threadIdx.x >> 7;    // 0..3 sub-reducer

    __shared__ float s_sum[4][128];
    __shared__ float s_cnt[4];
    __shared__ float s_red[8];

    float s = 0.0f;
    #pragma unroll 4
    for (int b = g; b < nblocks; b += 4)
        s += partial[(size_t)b * SLICE + c * DIM + t];
    s_sum[g][t] = s;

    float cn = 0.0f;
    for (int b = g; b < nblocks; b += 4)
        cn += partial[(size_t)b * SLICE + NCLS * DIM + c];
    if (t == 0) s_cnt[g] = cn;
    __syncthreads();

    float sq = 0.0f;
    const float cnt = ((s_cnt[0] + s_cnt[1]) + s_cnt[2]) + s_cnt[3];
    if (threadIdx.x < 128) {
        const float tot = ((s_sum[0][t] + s_sum[1][t]) + s_sum[2][t]) + s_sum[3][t];
        const int d = (t < 64) ? (2 * t) : (2 * t - 127);   // slot -> dim
        const float centroid = tot / fmaxf(cnt, 1.0f);
        const float dd = centers[c * DIM + d] - centroid;
        sq = dd * dd;
    }
    #pragma unroll
    for (int off = 32; off > 0; off >>= 1) sq += __shfl_xor(sq, off, 64);
    if ((threadIdx.x & 63) == 0) s_red[threadIdx.x >> 6] = sq;
    __syncthreads();
    if (threadIdx.x == 0) {
        const float total = s_red[0] + s_red[1];  // waves 2..7 contributed 0
        const float dist  = (total > 0.0f) ? sqrtf(total) : 0.0f;
        out[c] = (cnt > 0.0f) ? dist : 0.0f;
    }
}

extern "C" void kernel_launch(void* const* d_in, const int* in_sizes, int n_in,
                              void* d_out, int out_size, void* d_ws, size_t ws_size,
                              hipStream_t stream)
{
    const float* emb     = (const float*)d_in[0];  // [N, 128]
    const float* centers = (const float*)d_in[1];  // [100, 128]
    const float* logits  = (const float*)d_in[2];  // [N, 100]
    float* out = (float*)d_out;                    // [100]

    // workspace layout: assign [N ints, 4 MB] then block partials
    int*   assign  = (int*)d_ws;
    float* partial = (float*)((char*)d_ws + (size_t)NROWS * sizeof(int));

    size_t avail = (ws_size > (size_t)NROWS * sizeof(int))
                 ? ws_size - (size_t)NROWS * sizeof(int) : 0;
    int B = (int)(avail / (SLICE * sizeof(float)));
    if (B > 512) B = 512;
    if (B < 1)   B = 1;

    const int rows_per_block = (NROWS + B - 1) / B;

    l2cc_argmax<<<(NROWS + 63) / 64, 256, 0, stream>>>(logits, assign);
    l2cc_accum <<<B, P2_THREADS, 0, stream>>>(emb, assign, partial, rows_per_block);
    l2cc_final <<<NCLS, 512, 0, stream>>>(partial, centers, out, B);
}

// Round 7
// 301.166 us; speedup vs baseline: 2.5386x; 2.5386x over previous
//
#include <hip/hip_runtime.h>
#include <math.h>

// L2ClusterCentroid: N=1e6 rows, D=128, C=100.
// assign = argmax(logits, -1); centroids = segment_mean(embedding, assign);
// out[c] = counts[c]>0 ? ||centers[c] - centroids[c]||_2 : 0
//
// Round-7: K2 (LDS-atomic scatter) was 660us with 99.4% stall -> replaced by
// scan-gather: block (cluster c, slice s) scans assign (L2/L3-resident after
// first touch), ballots matches, gathers matched embedding rows coalesced,
// accumulates in PER-LANE REGISTERS. No atomics, no shuffles, no LDS in the
// hot loop (the proven-fast K1 pattern). Fixed scan order = bit-deterministic.

#define NROWS 1000000
#define DIM   128
#define NCLS  100
#define NSLICE 16
#define SLICE_ROWS (NROWS / NSLICE)   // 62500
#define PSTRIDE (DIM + 1)             // 129 floats per (cluster,slice) partial

// ---------------- K1: argmax over logits rows (unchanged, ~5 TB/s) ----------------
__global__ __launch_bounds__(256)
void l2cc_argmax(const float* __restrict__ logits, int* __restrict__ assign)
{
    const int tid = threadIdx.x;
    const int row = blockIdx.x * 64 + (tid >> 2);
    const int p   = tid & 3;
    if (row >= NROWS) return;

    const float4* lrow = reinterpret_cast<const float4*>(logits + (size_t)row * NCLS);
    float best = -INFINITY;
    int   bi   = 0x7fffffff;
    #pragma unroll
    for (int i = 0; i < 6; ++i) {
        const float4 v = lrow[i * 4 + p];       // cols 16i+4p .. +3
        const int c0 = i * 16 + p * 4;
        if (v.x > best) { best = v.x; bi = c0;     }
        if (v.y > best) { best = v.y; bi = c0 + 1; }
        if (v.z > best) { best = v.z; bi = c0 + 2; }
        if (v.w > best) { best = v.w; bi = c0 + 3; }
    }
    {   // tail cols 96..99
        const float t = logits[(size_t)row * NCLS + 96 + p];
        if (t > best) { best = t; bi = 96 + p; }
    }
    // merge across the 4 lanes of this row: quad_perm DPP, no LDS pipe
    #pragma unroll
    for (int off = 1; off <= 2; off <<= 1) {
        const float ov = __shfl_xor(best, off, 64);
        const int   oi = __shfl_xor(bi,   off, 64);
        if (ov > best || (ov == best && oi < bi)) { best = ov; bi = oi; }
    }
    if (p == 0) assign[row] = bi;
}

// ---------------- K2: scan-gather segment sum (register accumulation) ----------------
__global__ __launch_bounds__(256)
void l2cc_gather(const float* __restrict__ emb,
                 const int* __restrict__ assign,
                 float* __restrict__ partial)
{
    const int bid  = blockIdx.x;
    const int c    = bid / NSLICE;       // cluster this block owns
    const int sl   = bid % NSLICE;       // row-slice
    const int wave = threadIdx.x >> 6;
    const int lane = threadIdx.x & 63;

    const int start = sl * SLICE_ROWS;
    const int end   = start + SLICE_ROWS;

    float ax = 0.0f, ay = 0.0f, cnt = 0.0f;

    int r0 = start + wave * 64;
    int a  = -1;
    if (r0 < end) a = (lane < min(64, end - r0)) ? assign[r0 + lane] : -1;

    for (; r0 < end; r0 += 4 * 64) {
        // prefetch next chunk's assigns before processing matches
        const int rn = r0 + 4 * 64;
        int anext = -1;
        if (rn < end) anext = (lane < min(64, end - rn)) ? assign[rn + lane] : -1;

        unsigned long long m = __ballot(a == c);
        cnt += (float)__popcll(m);
        while (m) {
            const int j = __ffsll((long long)m) - 1;
            m &= m - 1;
            const float2 e = *reinterpret_cast<const float2*>(
                emb + (size_t)(r0 + j) * DIM + lane * 2);
            ax += e.x;
            ay += e.y;
        }
        a = anext;
    }

    // cross-wave reduce (fixed order, deterministic)
    __shared__ float sx[4][64], sy[4][64], sc[4];
    sx[wave][lane] = ax;
    sy[wave][lane] = ay;
    if (lane == 0) sc[wave] = cnt;
    __syncthreads();
    if (wave == 0) {
        const float fx = ((sx[0][lane] + sx[1][lane]) + sx[2][lane]) + sx[3][lane];
        const float fy = ((sy[0][lane] + sy[1][lane]) + sy[2][lane]) + sy[3][lane];
        float* p = partial + (size_t)bid * PSTRIDE;
        reinterpret_cast<float2*>(p)[lane] = make_float2(fx, fy);   // dims 2*lane, 2*lane+1
        if (lane == 0) p[DIM] = ((sc[0] + sc[1]) + sc[2]) + sc[3];
    }
}

// ---------------- K3: per-cluster slice reduction + distance epilogue ----------------
__global__ __launch_bounds__(128)
void l2cc_final(const float* __restrict__ partial,
                const float* __restrict__ centers,
                float* __restrict__ out)
{
    const int c = blockIdx.x;     // 0..99
    const int t = threadIdx.x;    // 0..127 = dim

    float s = 0.0f, cnt = 0.0f;
    #pragma unroll
    for (int sl = 0; sl < NSLICE; ++sl) {
        const float* p = partial + (size_t)(c * NSLICE + sl) * PSTRIDE;
        s   += p[t];
        cnt += p[DIM];
    }

    const float centroid = s / fmaxf(cnt, 1.0f);
    const float dd = centers[c * DIM + t] - centroid;
    float sq = dd * dd;
    #pragma unroll
    for (int off = 32; off > 0; off >>= 1) sq += __shfl_xor(sq, off, 64);

    __shared__ float red[2];
    if ((t & 63) == 0) red[t >> 6] = sq;
    __syncthreads();
    if (t == 0) {
        const float total = red[0] + red[1];
        out[c] = (cnt > 0.0f && total > 0.0f) ? sqrtf(total) : 0.0f;
    }
}

extern "C" void kernel_launch(void* const* d_in, const int* in_sizes, int n_in,
                              void* d_out, int out_size, void* d_ws, size_t ws_size,
                              hipStream_t stream)
{
    const float* emb     = (const float*)d_in[0];  // [N, 128]
    const float* centers = (const float*)d_in[1];  // [100, 128]
    const float* logits  = (const float*)d_in[2];  // [N, 100]
    float* out = (float*)d_out;                    // [100]

    // workspace layout: assign [N ints, 4 MB] then partials [1600][129] f32 (~826 KB)
    int*   assign  = (int*)d_ws;
    float* partial = (float*)((char*)d_ws + (size_t)NROWS * sizeof(int));

    l2cc_argmax<<<(NROWS + 63) / 64, 256, 0, stream>>>(logits, assign);
    l2cc_gather<<<NCLS * NSLICE, 256, 0, stream>>>(emb, assign, partial);
    l2cc_final <<<NCLS, 128, 0, stream>>>(partial, centers, out);
}

// Round 8
// 191.327 us; speedup vs baseline: 3.9960x; 1.5741x over previous
//
#include <hip/hip_runtime.h>
#include <math.h>

// L2ClusterCentroid: N=1e6 rows, D=128, C=100.
// assign = argmax(logits, -1); centroids = segment_mean(embedding, assign);
// out[c] = counts[c]>0 ? ||centers[c] - centroids[c]||_2 : 0
//
// Round-8: round-7 gather was ~210us (2.5 TB/s): (a) 1-chunk assign prefetch
// -> L2 latency per 64 rows; (b) while(m) matched loads -> vmcnt(0) per row.
// Now: 4-chunk (256-row) assign prefetch + LDS match-queue with 16-deep
// batched drains (16 independent row loads in flight per drain). Queue order
// = row order -> bit-deterministic. K1/K3 unchanged (K1 ~85us @ ~5TB/s).

#define NROWS 1000000
#define DIM   128
#define NCLS  100
#define NSLICE 16
#define SLICE_ROWS (NROWS / NSLICE)   // 62500
#define PSTRIDE (DIM + 2)             // 130 floats (even -> float2-aligned)
#define QCAP  128
#define QMASK 127
#define DRAINN 16

// ---------------- K1: argmax over logits rows (~5 TB/s, keep) ----------------
__global__ __launch_bounds__(256)
void l2cc_argmax(const float* __restrict__ logits, int* __restrict__ assign)
{
    const int tid = threadIdx.x;
    const int row = blockIdx.x * 64 + (tid >> 2);
    const int p   = tid & 3;
    if (row >= NROWS) return;

    const float4* lrow = reinterpret_cast<const float4*>(logits + (size_t)row * NCLS);
    float best = -INFINITY;
    int   bi   = 0x7fffffff;
    #pragma unroll
    for (int i = 0; i < 6; ++i) {
        const float4 v = lrow[i * 4 + p];       // cols 16i+4p .. +3
        const int c0 = i * 16 + p * 4;
        if (v.x > best) { best = v.x; bi = c0;     }
        if (v.y > best) { best = v.y; bi = c0 + 1; }
        if (v.z > best) { best = v.z; bi = c0 + 2; }
        if (v.w > best) { best = v.w; bi = c0 + 3; }
    }
    {   // tail cols 96..99
        const float t = logits[(size_t)row * NCLS + 96 + p];
        if (t > best) { best = t; bi = 96 + p; }
    }
    #pragma unroll
    for (int off = 1; off <= 2; off <<= 1) {    // quad_perm DPP merge
        const float ov = __shfl_xor(best, off, 64);
        const int   oi = __shfl_xor(bi,   off, 64);
        if (ov > best || (ov == best && oi < bi)) { best = ov; bi = oi; }
    }
    if (p == 0) assign[row] = bi;
}

// ---------------- K2: scan + queued batch-gather ----------------
#define LDROW(R) *reinterpret_cast<const float2*>(emb + (size_t)(R) * DIM + lane * 2)

#define DRAIN16                                                              \
    {                                                                        \
        const int i0  = q[wave][(qhead+ 0)&QMASK], i1  = q[wave][(qhead+ 1)&QMASK]; \
        const int i2  = q[wave][(qhead+ 2)&QMASK], i3  = q[wave][(qhead+ 3)&QMASK]; \
        const int i4  = q[wave][(qhead+ 4)&QMASK], i5  = q[wave][(qhead+ 5)&QMASK]; \
        const int i6  = q[wave][(qhead+ 6)&QMASK], i7  = q[wave][(qhead+ 7)&QMASK]; \
        const int i8  = q[wave][(qhead+ 8)&QMASK], i9  = q[wave][(qhead+ 9)&QMASK]; \
        const int i10 = q[wave][(qhead+10)&QMASK], i11 = q[wave][(qhead+11)&QMASK]; \
        const int i12 = q[wave][(qhead+12)&QMASK], i13 = q[wave][(qhead+13)&QMASK]; \
        const int i14 = q[wave][(qhead+14)&QMASK], i15 = q[wave][(qhead+15)&QMASK]; \
        const float2 e0 = LDROW(i0),  e1 = LDROW(i1),  e2 = LDROW(i2),  e3 = LDROW(i3); \
        const float2 e4 = LDROW(i4),  e5 = LDROW(i5),  e6 = LDROW(i6),  e7 = LDROW(i7); \
        const float2 e8 = LDROW(i8),  e9 = LDROW(i9),  e10= LDROW(i10), e11= LDROW(i11);\
        const float2 e12= LDROW(i12), e13= LDROW(i13), e14= LDROW(i14), e15= LDROW(i15);\
        ax += e0.x;  ay += e0.y;  ax += e1.x;  ay += e1.y;                   \
        ax += e2.x;  ay += e2.y;  ax += e3.x;  ay += e3.y;                   \
        ax += e4.x;  ay += e4.y;  ax += e5.x;  ay += e5.y;                   \
        ax += e6.x;  ay += e6.y;  ax += e7.x;  ay += e7.y;                   \
        ax += e8.x;  ay += e8.y;  ax += e9.x;  ay += e9.y;                   \
        ax += e10.x; ay += e10.y; ax += e11.x; ay += e11.y;                  \
        ax += e12.x; ay += e12.y; ax += e13.x; ay += e13.y;                  \
        ax += e14.x; ay += e14.y; ax += e15.x; ay += e15.y;                  \
        qhead += 16;                                                         \
    }

#define PUSH(AV, OFF)                                                        \
    {                                                                        \
        const unsigned long long m_ = __ballot((AV) == c);                   \
        if ((AV) == c) {                                                     \
            const int rank_ = __popcll(m_ & ((1ull << lane) - 1ull));        \
            q[wave][(qtail + rank_) & QMASK] = rw + (OFF) + lane;            \
        }                                                                    \
        const int pc_ = __popcll(m_);                                        \
        qtail += pc_; icnt += pc_;                                           \
        while (qtail - qhead >= DRAINN) DRAIN16                              \
    }

__global__ __launch_bounds__(256)
void l2cc_gather(const float* __restrict__ emb,
                 const int* __restrict__ assign,
                 float* __restrict__ partial)
{
    const int bid  = blockIdx.x;
    const int c    = bid / NSLICE;       // cluster this block owns
    const int sl   = bid - c * NSLICE;   // row-slice
    const int wave = threadIdx.x >> 6;
    const int lane = threadIdx.x & 63;

    __shared__ int   q[4][QCAP];         // per-wave matched-row-id ring
    __shared__ float sx[4][64], sy[4][64];
    __shared__ int   scnt[4];

    const int start = sl * SLICE_ROWS;
    const int end   = start + SLICE_ROWS;

    float ax = 0.0f, ay = 0.0f;
    int   icnt = 0, qhead = 0, qtail = 0;

    int rw = start + wave * 256;
    int a0 = (rw +   0 + lane < end) ? assign[rw +   0 + lane] : -1;
    int a1 = (rw +  64 + lane < end) ? assign[rw +  64 + lane] : -1;
    int a2 = (rw + 128 + lane < end) ? assign[rw + 128 + lane] : -1;
    int a3 = (rw + 192 + lane < end) ? assign[rw + 192 + lane] : -1;

    for (; rw < end; rw += 1024) {
        const int rn = rw + 1024;        // prefetch next 256-row group
        int b0 = -1, b1 = -1, b2 = -1, b3 = -1;
        if (rn < end) {
            b0 = (rn +   0 + lane < end) ? assign[rn +   0 + lane] : -1;
            b1 = (rn +  64 + lane < end) ? assign[rn +  64 + lane] : -1;
            b2 = (rn + 128 + lane < end) ? assign[rn + 128 + lane] : -1;
            b3 = (rn + 192 + lane < end) ? assign[rn + 192 + lane] : -1;
        }

        PUSH(a0, 0) PUSH(a1, 64) PUSH(a2, 128) PUSH(a3, 192)

        a0 = b0; a1 = b1; a2 = b2; a3 = b3;
    }

    // tail: drain remaining queued rows one at a time (fixed order)
    while (qtail > qhead) {
        const int r = q[wave][qhead & QMASK]; ++qhead;
        const float2 e = LDROW(r);
        ax += e.x; ay += e.y;
    }

    // cross-wave reduce (fixed order, deterministic)
    sx[wave][lane] = ax;
    sy[wave][lane] = ay;
    if (lane == 0) scnt[wave] = icnt;
    __syncthreads();
    if (wave == 0) {
        const float fx = ((sx[0][lane] + sx[1][lane]) + sx[2][lane]) + sx[3][lane];
        const float fy = ((sy[0][lane] + sy[1][lane]) + sy[2][lane]) + sy[3][lane];
        float* p = partial + (size_t)bid * PSTRIDE;
        reinterpret_cast<float2*>(p)[lane] = make_float2(fx, fy);  // dims 2l, 2l+1
        if (lane == 0)
            p[DIM] = (float)(((scnt[0] + scnt[1]) + scnt[2]) + scnt[3]);
    }
}

// ---------------- K3: per-cluster slice reduction + distance epilogue ----------------
__global__ __launch_bounds__(128)
void l2cc_final(const float* __restrict__ partial,
                const float* __restrict__ centers,
                float* __restrict__ out)
{
    const int c = blockIdx.x;     // 0..99
    const int t = threadIdx.x;    // 0..127 = dim

    float s = 0.0f, cnt = 0.0f;
    #pragma unroll
    for (int sl = 0; sl < NSLICE; ++sl) {
        const float* p = partial + (size_t)(c * NSLICE + sl) * PSTRIDE;
        s   += p[t];
        cnt += p[DIM];
    }

    const float centroid = s / fmaxf(cnt, 1.0f);
    const float dd = centers[c * DIM + t] - centroid;
    float sq = dd * dd;
    #pragma unroll
    for (int off = 32; off > 0; off >>= 1) sq += __shfl_xor(sq, off, 64);

    __shared__ float red[2];
    if ((t & 63) == 0) red[t >> 6] = sq;
    __syncthreads();
    if (t == 0) {
        const float total = red[0] + red[1];
        out[c] = (cnt > 0.0f && total > 0.0f) ? sqrtf(total) : 0.0f;
    }
}

extern "C" void kernel_launch(void* const* d_in, const int* in_sizes, int n_in,
                              void* d_out, int out_size, void* d_ws, size_t ws_size,
                              hipStream_t stream)
{
    const float* emb     = (const float*)d_in[0];  // [N, 128]
    const float* centers = (const float*)d_in[1];  // [100, 128]
    const float* logits  = (const float*)d_in[2];  // [N, 100]
    float* out = (float*)d_out;                    // [100]

    // workspace: assign [N ints, 4 MB] then partials [1600][130] f32 (~832 KB)
    int*   assign  = (int*)d_ws;
    float* partial = (float*)((char*)d_ws + (size_t)NROWS * sizeof(int));

    l2cc_argmax<<<(NROWS + 63) / 64, 256, 0, stream>>>(logits, assign);
    l2cc_gather<<<NCLS * NSLICE, 256, 0, stream>>>(emb, assign, partial);
    l2cc_final <<<NCLS, 128, 0, stream>>>(partial, centers, out);
}